// Round 15
// baseline (276.761 us; speedup 1.0000x reference)
//
#include <hip/hip_runtime.h>
#include <math.h>

#define N_NODES 1024
#define B_SZ 64
#define GNH 4096     // half-width: b*64+c layout for X or S plane
#define KI 384       // 3*128
#define EDIM 16
// stream-ordered Wt layouts (fp16 units per node)
#define WG_NODE 49152   // gate: 128 o x 384 k
#define WG_WAVE 12288   // per (n,wave)
#define WU_NODE 24576   // upd: 64 o x 384 k
#define WU_WAVE 6144

typedef _Float16 half8_t __attribute__((ext_vector_type(8)));
typedef float f32x4 __attribute__((ext_vector_type(4)));

__device__ __forceinline__ unsigned short f2h(float f) {
    _Float16 h = (_Float16)f;
    return *(unsigned short*)&h;
}
__device__ __forceinline__ float h2f(unsigned short u) {
    _Float16 h = *(_Float16*)&u;
    return (float)h;
}
__device__ __forceinline__ float sigmoidf_(float v) {
    return 1.f / (1.f + __expf(-v));
}
// async global->LDS, 16B per lane; lds base must be wave-uniform.
__device__ __forceinline__ void load_lds16(const void* g, void* l) {
    __builtin_amdgcn_global_load_lds(
        (const __attribute__((address_space(1))) void*)g,
        (__attribute__((address_space(3))) void*)l, 16, 0, 0);
}

// ---------------------------------------------------------------------------
// FUSED PREP (grid-partitioned, NO cross-role barriers). Roles are STRIPED
// across blockIdx (17-block groups: 4 compute_A, 4 build_T0, 6 dq-gate,
// 3 dq-upd) so every CU holds a mix of VALU-bound and BW-bound blocks
// concurrently -- R13/R14 range-based assignment executed the phases
// nearly serially (both VALUBusy and HBM under 40%).
//   role0 x1024: compute_A   : Ah = softmax(relu(E E^T)) rows
//   role1 x1024: build_T0    : TX0/TS0 + TX0T/TS0T from x,state
//   role2 x1536: dequant gate: WtG (stream-ordered)
//   role3 x 768: dequant upd : WtU (stream-ordered)
// ---------------------------------------------------------------------------
__global__ __launch_bounds__(256) void fused_prep_kernel(
    const float* __restrict__ x, const float* __restrict__ state,
    const float* __restrict__ E, const float* __restrict__ gW,
    const float* __restrict__ uW, unsigned short* __restrict__ Ah,
    unsigned short* __restrict__ TX0, unsigned short* __restrict__ TS0,
    unsigned short* __restrict__ TX0T, unsigned short* __restrict__ TS0T,
    unsigned short* __restrict__ WtG, unsigned short* __restrict__ WtU) {
    __shared__ __align__(16) unsigned short sh[64 * 72 * 2];  // 18 KB scratch
    const int tid = threadIdx.x;
    // role striping: 4352 = 17 * 256 groups of {4,4,6,3}
    const int grp = blockIdx.x / 17;
    const int s17 = blockIdx.x % 17;

    if (s17 < 4) {
        // ===================== compute_A =====================
        float* red = (float*)sh;
        const int n = grp * 4 + s17;
        float en[EDIM];
#pragma unroll
        for (int e = 0; e < EDIM; ++e) en[e] = E[n * EDIM + e];
        float logit[4], lmax = -1e30f;
#pragma unroll
        for (int j = 0; j < 4; ++j) {
            const int m = tid + j * 256;
            float d = 0.f;
#pragma unroll
            for (int e = 0; e < EDIM; ++e) d += en[e] * E[m * EDIM + e];
            d = fmaxf(d, 0.f);
            logit[j] = d;
            lmax = fmaxf(lmax, d);
        }
        red[tid] = lmax;
        __syncthreads();
        for (int s = 128; s > 0; s >>= 1) {
            if (tid < s) red[tid] = fmaxf(red[tid], red[tid + s]);
            __syncthreads();
        }
        lmax = red[0];
        __syncthreads();
        float ex[4], lsum = 0.f;
#pragma unroll
        for (int j = 0; j < 4; ++j) {
            ex[j] = __expf(logit[j] - lmax);
            lsum += ex[j];
        }
        red[tid] = lsum;
        __syncthreads();
        for (int s = 128; s > 0; s >>= 1) {
            if (tid < s) red[tid] += red[tid + s];
            __syncthreads();
        }
        const float inv = 1.f / red[0];
#pragma unroll
        for (int j = 0; j < 4; ++j)
            Ah[n * N_NODES + tid + j * 256] = f2h(ex[j] * inv);
    } else if (s17 < 8) {
        // ===================== build_T0 =====================
        unsigned short* Lx = sh;             // [c][nl] pad 72
        unsigned short* Lss = sh + 64 * 72;
        const int idx = grp * 4 + (s17 - 4);
        const int n0 = (idx & 15) * 64;
        const int b = idx >> 4;
#pragma unroll
        for (int t = 0; t < 16; ++t) {
            const int id = t * 256 + tid;
            const int nl = id >> 6;
            const int c = id & 63;
            const float xv = x[((size_t)b * N_NODES + n0 + nl) * 64 + c];
            const float sv = state[((size_t)b * N_NODES + n0 + nl) * 64 + c];
            const unsigned short xh = f2h(xv), shv = f2h(sv);
            TX0[(size_t)(n0 + nl) * GNH + b * 64 + c] = xh;
            TS0[(size_t)(n0 + nl) * GNH + b * 64 + c] = shv;
            Lx[c * 72 + nl] = xh;
            Lss[c * 72 + nl] = shv;
        }
        __syncthreads();
#pragma unroll
        for (int t = 0; t < 2; ++t) {
            const int id = t * 256 + tid;
            const int c = id >> 3;
            const int n8 = id & 7;
            uint4 xv = *(const uint4*)&Lx[c * 72 + n8 * 8];
            uint4 sv = *(const uint4*)&Lss[c * 72 + n8 * 8];
            *(uint4*)&TX0T[(size_t)(b * 64 + c) * N_NODES + n0 + n8 * 8] = xv;
            *(uint4*)&TS0T[(size_t)(b * 64 + c) * N_NODES + n0 + n8 * 8] = sv;
        }
    } else if (s17 < 14) {
        // ===================== dequant gate =====================
        float* En = (float*)sh;
        const int idx = grp * 6 + (s17 - 8);
        const int c8 = (idx % 48) * 256 + tid;  // 0..12287
        const int n0 = (idx / 48) * 32;
        const int sub = c8 & 1;
        const int c = c8 >> 1;
        const int l15 = c & 15;
        const int quad = (c >> 4) & 3;
        const int half = (c >> 6) & 1;
        const int ks = (c >> 7) & 3;
        const int sq = c >> 9;
        const int s = sq % 3;
        const int w = sq / 3;
        const int k0 = s * 128 + (ks * 4 + quad) * 8 + sub * 4;
        const int o = w * 32 + half * 16 + l15;
#pragma unroll
        for (int t = 0; t < 2; ++t) {
            const int id = t * 256 + tid;
            En[id] = E[(n0 + (id >> 4)) * EDIM + (id & 15)];
        }
        __syncthreads();
        f32x4 wv[EDIM];
#pragma unroll
        for (int e = 0; e < EDIM; ++e) {
            f32x4 v;
#pragma unroll
            for (int j = 0; j < 4; ++j)
                v[j] = gW[(size_t)(e * KI + k0 + j) * 128 + o];
            wv[e] = v;
        }
#pragma unroll 4
        for (int nl = 0; nl < 32; ++nl) {
            f32x4 a = {0.f, 0.f, 0.f, 0.f};
#pragma unroll
            for (int e = 0; e < EDIM; ++e) a += wv[e] * En[nl * EDIM + e];
            union { unsigned short u[4]; uint2 v; } pk;
#pragma unroll
            for (int j = 0; j < 4; ++j) pk.u[j] = f2h(a[j]);
            *(uint2*)&WtG[(size_t)(n0 + nl) * WG_NODE + (size_t)c8 * 4] = pk.v;
        }
    } else {
        // ===================== dequant upd =====================
        float* En = (float*)sh;
        const int idx = grp * 3 + (s17 - 14);
        const int c8 = (idx % 24) * 256 + tid;  // 0..6143
        const int n0 = (idx / 24) * 32;
        const int sub = c8 & 1;
        const int c = c8 >> 1;
        const int l15 = c & 15;
        const int quad = (c >> 4) & 3;
        const int ks = (c >> 6) & 3;
        const int sq = c >> 8;
        const int s = sq % 3;
        const int w = sq / 3;
        const int k0 = s * 128 + (ks * 4 + quad) * 8 + sub * 4;
        const int o = w * 16 + l15;
#pragma unroll
        for (int t = 0; t < 2; ++t) {
            const int id = t * 256 + tid;
            En[id] = E[(n0 + (id >> 4)) * EDIM + (id & 15)];
        }
        __syncthreads();
        f32x4 wv[EDIM];
#pragma unroll
        for (int e = 0; e < EDIM; ++e) {
            f32x4 v;
#pragma unroll
            for (int j = 0; j < 4; ++j)
                v[j] = uW[(size_t)(e * KI + k0 + j) * 64 + o];
            wv[e] = v;
        }
#pragma unroll 4
        for (int nl = 0; nl < 32; ++nl) {
            f32x4 a = {0.f, 0.f, 0.f, 0.f};
#pragma unroll
            for (int e = 0; e < EDIM; ++e) a += wv[e] * En[nl * EDIM + e];
            union { unsigned short u[4]; uint2 v; } pk;
#pragma unroll
            for (int j = 0; j < 4; ++j) pk.u[j] = f2h(a[j]);
            *(uint2*)&WtU[(size_t)(n0 + nl) * WU_NODE + (size_t)c8 * 4] = pk.v;
        }
    }
}

// ---------------------------------------------------------------------------
// Generic fp16 transpose: dst[c][1024] = src[r][W], 64x64 tiles.
// ---------------------------------------------------------------------------
__global__ __launch_bounds__(256) void transpose16_kernel(
    const unsigned short* __restrict__ src, unsigned short* __restrict__ dst,
    int W) {
    __shared__ unsigned short Ls[64 * 72];
    const int tid = threadIdx.x;
    const int r0 = blockIdx.x * 64;
    const int c0 = blockIdx.y * 64;
#pragma unroll
    for (int t = 0; t < 2; ++t) {
        const int id = t * 256 + tid;
        const int row = id >> 3;
        const int c8 = id & 7;
        uint4 v = *(const uint4*)&src[(size_t)(r0 + row) * W + c0 + c8 * 8];
        const unsigned short* vp = (const unsigned short*)&v;
#pragma unroll
        for (int j = 0; j < 8; ++j) Ls[(c8 * 8 + j) * 72 + row] = vp[j];
    }
    __syncthreads();
#pragma unroll
    for (int t = 0; t < 2; ++t) {
        const int id = t * 256 + tid;
        const int c = id >> 3;
        const int r8 = id & 7;
        uint4 v = *(const uint4*)&Ls[c * 72 + r8 * 8];
        *(uint4*)&dst[(size_t)(c0 + c) * N_NODES + r0 + r8 * 8] = v;
    }
}

// ---------------------------------------------------------------------------
// S2h[n][m] = 2 * sum_k Ah[n][k]*AhT[m][k] - (n==m)   (S2 = 2A^2 - I)
// ---------------------------------------------------------------------------
__global__ __launch_bounds__(256) void gemm_s2_kernel(
    const unsigned short* __restrict__ Ah,
    const unsigned short* __restrict__ AhT, unsigned short* __restrict__ S2h) {
    __shared__ unsigned short As[64 * 64];
    __shared__ unsigned short Bs[64 * 64];
    const int tid = threadIdx.x;
    const int wave = tid >> 6;
    const int lane = tid & 63;
    const int l15 = lane & 15;
    const int quad = lane >> 4;
    const int n0 = blockIdx.x * 64;
    const int m0 = blockIdx.y * 64;
    const int wn = wave * 16;
    const int lr = lane >> 3;
    const int lsw = (lane & 7) ^ lr;

    f32x4 acc[4] = {};
    for (int k0 = 0; k0 < N_NODES; k0 += 64) {
#pragma unroll
        for (int i = 0; i < 2; ++i) {
            const int rbase = (wave * 2 + i) * 8;
            load_lds16(&Ah[(size_t)(n0 + rbase + lr) * N_NODES + k0 + lsw * 8],
                       &As[rbase * 64]);
            load_lds16(&AhT[(size_t)(m0 + rbase + lr) * N_NODES + k0 + lsw * 8],
                       &Bs[rbase * 64]);
        }
        __syncthreads();
#pragma unroll
        for (int ks = 0; ks < 2; ++ks) {
            const int slot = ((ks * 4 + quad) ^ (l15 & 7)) * 8;
            const half8_t b = *(const half8_t*)&Bs[(wn + l15) * 64 + slot];
#pragma unroll
            for (int mi = 0; mi < 4; ++mi) {
                const half8_t a = *(const half8_t*)&As[(mi * 16 + l15) * 64 + slot];
                acc[mi] =
                    __builtin_amdgcn_mfma_f32_16x16x32_f16(a, b, acc[mi], 0, 0, 0);
            }
        }
        __syncthreads();
    }
#pragma unroll
    for (int mi = 0; mi < 4; ++mi) {
#pragma unroll
        for (int r = 0; r < 4; ++r) {
            const int n_g = n0 + mi * 16 + quad * 4 + r;
            const int m_g = m0 + wn + l15;
            const float v = 2.f * acc[mi][r] - (n_g == m_g ? 1.f : 0.f);
            S2h[(size_t)n_g * N_NODES + m_g] = f2h(v);
        }
    }
}

// ---------------------------------------------------------------------------
// Graph GEMM, pipelined ring-4 with SINGLE phase per K-tile (R8-proven):
//   {ds_read all 8A+4B frags || stage A+B(t+3) -> lgkm0 -> setprio(1)
//    32 MFMA setprio(0) -> counted vmcnt -> ONE barrier}.
// ---------------------------------------------------------------------------
template <int BM>
__global__ __launch_bounds__(512, 2) void gemm_graph8_kernel(
    const unsigned short* __restrict__ Ah,
    const unsigned short* __restrict__ S2h,
    const unsigned short* __restrict__ BTX,
    const unsigned short* __restrict__ BTS,
    unsigned short* __restrict__ T1X, unsigned short* __restrict__ T1S,
    unsigned short* __restrict__ T2X, unsigned short* __restrict__ T2S,
    int ysplit, int colsPerXcd) {
    constexpr int MFR = BM / 32;        // A frags per wave (8 or 4)
    constexpr int ASLOT_H = BM * 32;    // f16 per A slot (BM/2 prows x 64)
    constexpr int SLOT_H = ASLOT_H + 8192;  // + B slot (128 prows x 64)
    constexpr int APASS = BM / 128;     // stage passes for A (2 or 1)
    constexpr int MT = 2048 / BM;       // row tiles
    __shared__ unsigned short lds[4 * SLOT_H];  // 128 KB (BM=256) / 96 KB

    const int tid = threadIdx.x;
    const int wave = tid >> 6;
    const int lane = tid & 63;
    const int l15 = lane & 15;
    const int quad = lane >> 4;
    const int wm = (wave >> 2) * (BM / 2);
    const int wn = (wave & 3) * 64;

    // XCD-locality swizzle: xcd owns colsPerXcd 256-col tiles x all row tiles
    const int id = blockIdx.x;
    const int xcd = id & 7;
    const int j = id >> 3;
    const int mtile = j & (MT - 1);
    const int ytile = xcd * colsPerXcd + j / MT;
    const int mrow0 = mtile * BM;
    const bool isA = mrow0 < N_NODES;
    const unsigned short* Asrc =
        (isA ? Ah : S2h) + (size_t)(mrow0 & 1023) * N_NODES;
    const bool isX = ytile < ysplit;
    const int col0 = (isX ? ytile : ytile - ysplit) * 256;
    const unsigned short* Bsrc = (isX ? BTX : BTS) + (size_t)col0 * N_NODES;
    unsigned short* OUT = (isA ? (isX ? T1X : T1S) : (isX ? T2X : T2S)) +
                          (size_t)(mrow0 & 1023) * GNH + col0;

    // stage source offsets: physical cell (prow, s) <- logical
    // (row = 2*prow + half, kslot) with half*4+kslot = s ^ (prow&7)
    int goff[2];
#pragma unroll
    for (int jp = 0; jp < 2; ++jp) {
        const int cell = jp * 512 + tid;
        const int prow = cell >> 3;
        const int q = (cell & 7) ^ (prow & 7);
        goff[jp] = (2 * prow + (q >> 2)) * N_NODES + (q & 3) * 8;
    }

    // ds_read fragment offsets (f16 units): row R -> prow=R>>1, half=R&1,
    // s8 = (half*4 + quad) ^ (prow&7)
    int offA[MFR], offB[4];
#pragma unroll
    for (int mi = 0; mi < MFR; ++mi) {
        const int prow = (wm >> 1) + mi * 8 + (l15 >> 1);
        const int s8 = ((l15 & 1) * 4 + quad) ^ (prow & 7);
        offA[mi] = prow * 64 + s8 * 8;
    }
#pragma unroll
    for (int ni = 0; ni < 4; ++ni) {
        const int pcol = (wn >> 1) + ni * 8 + (l15 >> 1);
        const int s8 = ((l15 & 1) * 4 + quad) ^ (pcol & 7);
        offB[ni] = ASLOT_H + pcol * 64 + s8 * 8;
    }

    f32x4 acc[MFR][4] = {};

    auto stageA = [&](int t) {
        const int sl = t & 3;
#pragma unroll
        for (int jp = 0; jp < APASS; ++jp)
            load_lds16(Asrc + (size_t)t * 32 + goff[jp],
                       &lds[sl * SLOT_H + jp * 4096 + wave * 512]);
    };
    auto stageB = [&](int t) {
        const int sl = t & 3;
#pragma unroll
        for (int jp = 0; jp < 2; ++jp)
            load_lds16(Bsrc + (size_t)t * 32 + goff[jp],
                       &lds[sl * SLOT_H + ASLOT_H + jp * 4096 + wave * 512]);
    };
    // counted vmcnt: allow the newest 2 tiles' stages (2*LPT instrs) in flight
    auto waitPipe = [&] {
        if constexpr (BM == 256)
            asm volatile("s_waitcnt vmcnt(8)" ::: "memory");
        else
            asm volatile("s_waitcnt vmcnt(6)" ::: "memory");
    };

    auto tileBody = [&](int t, bool tail) {
        const unsigned short* base = &lds[(t & 3) * SLOT_H];
        half8_t a[MFR], b[4];
        // read ALL fragments for this tile (slot certified by prev barrier)
#pragma unroll
        for (int mi = 0; mi < MFR; ++mi)
            a[mi] = *(const half8_t*)&base[offA[mi]];
#pragma unroll
        for (int ni = 0; ni < 4; ++ni)
            b[ni] = *(const half8_t*)&base[offB[ni]];
        // issue next-tile stages (write slot (t-1)&3: safe -- all waves
        // passed lgkm0 for tile t-1 before the trailing barrier of t-1)
        if (!tail) {
            stageA(t + 3);
            stageB(t + 3);
        }
        __builtin_amdgcn_sched_barrier(0);
        asm volatile("s_waitcnt lgkmcnt(0)" ::: "memory");
        __builtin_amdgcn_sched_barrier(0);
        __builtin_amdgcn_s_setprio(1);
#pragma unroll
        for (int mi = 0; mi < MFR; ++mi)
#pragma unroll
            for (int ni = 0; ni < 4; ++ni)
                acc[mi][ni] = __builtin_amdgcn_mfma_f32_16x16x32_f16(
                    a[mi], b[ni], acc[mi][ni], 0, 0, 0);
        __builtin_amdgcn_s_setprio(0);
        __builtin_amdgcn_sched_barrier(0);
        if (!tail) {
            waitPipe();  // tile t+1 landed; t+2,t+3 stay in flight
        } else {
            asm volatile("s_waitcnt vmcnt(0)" ::: "memory");
        }
        __builtin_amdgcn_sched_barrier(0);
        __builtin_amdgcn_s_barrier();  // ONE barrier per K-tile
    };

    // prologue: stage tiles 0..2, wait for tile 0 (tiles 1,2 stay in flight)
    stageA(0); stageB(0);
    stageA(1); stageB(1);
    stageA(2); stageB(2);
    waitPipe();
    __builtin_amdgcn_s_barrier();
    __builtin_amdgcn_sched_barrier(0);

    // K = 1024 -> 32 tiles of BK=32
#pragma unroll 4
    for (int t = 0; t < 28; ++t) tileBody(t, false);
    tileBody(28, false);
    tileBody(29, true);
    tileBody(30, true);
    tileBody(31, true);

    // epilogue: 64-row passes through LDS repack -> coalesced uint4 stores
    constexpr int NPASS = BM / 64;
#pragma unroll
    for (int p = 0; p < NPASS; ++p) {
        __syncthreads();
        const int whalf = (BM == 256) ? (p >> 1) : p;
        const int mi0 = (BM == 256) ? (p & 1) * 4 : 0;
        if ((wave >> 2) == whalf) {
#pragma unroll
            for (int mi = 0; mi < 4; ++mi)
#pragma unroll
                for (int ni = 0; ni < 4; ++ni)
#pragma unroll
                    for (int r = 0; r < 4; ++r) {
                        const int row = mi * 16 + quad * 4 + r;
                        const int col = wn + ni * 16 + l15;
                        lds[row * 264 + col] = f2h(acc[mi0 + mi][ni][r]);
                    }
        }
        __syncthreads();
#pragma unroll
        for (int i = 0; i < 4; ++i) {
            const int id2 = i * 512 + tid;
            const int row = id2 >> 5;
            const int c8 = id2 & 31;
            uint4 v = *(const uint4*)&lds[row * 264 + c8 * 8];
            *(uint4*)&OUT[(size_t)(p * 64 + row) * GNH + c8 * 8] = v;
        }
    }
}

// ---------------------------------------------------------------------------
// Gate per-node GEMM (merged z+r): M=64(b), N=128(o), K=384. R2 schedule,
// W reads from the stream-ordered layout: contiguous 1KB per instruction,
// contiguous 24KB per wave. z -> CAND (z*state), r -> rbuf.
// ---------------------------------------------------------------------------
__global__ __launch_bounds__(256) void pernode_gate_kernel(
    const unsigned short* __restrict__ TX0,
    const unsigned short* __restrict__ TS0,
    const unsigned short* __restrict__ TX1,
    const unsigned short* __restrict__ TS1,
    const unsigned short* __restrict__ TX2,
    const unsigned short* __restrict__ TS2,
    const unsigned short* __restrict__ Wt, const float* __restrict__ E,
    const float* __restrict__ bp, const float* __restrict__ state,
    unsigned short* __restrict__ rbuf, unsigned short* __restrict__ cand) {
    __shared__ unsigned short XsX[64 * 64];  // [b][kseg 0..7] swizzled
    __shared__ unsigned short XsS[64 * 64];  // [b][kseg 8..15] swizzled
    const int n = blockIdx.x;
    const int tid = threadIdx.x;
    const int wave = tid >> 6;
    const int lane = tid & 63;
    const int l15 = lane & 15;
    const int quad = lane >> 4;
    const int wn = wave * 32;
    const int lr = lane >> 3;
    const int lsw = (lane & 7) ^ lr;

    float bias[2];
#pragma unroll
    for (int ni = 0; ni < 2; ++ni) {
        float bv = 0.f;
#pragma unroll
        for (int e = 0; e < EDIM; ++e)
            bv += E[n * EDIM + e] * bp[e * 128 + wn + ni * 16 + l15];
        bias[ni] = bv;
    }

    f32x4 acc[4][2] = {};

    const unsigned short* TXs[3] = {TX0, TX1, TX2};
    const unsigned short* TSs[3] = {TS0, TS1, TS2};
    const unsigned short* wbase =
        Wt + ((size_t)n * 4 + wave) * WG_WAVE + lane * 8;

    for (int s = 0; s < 3; ++s) {
        const unsigned short* xs = TXs[s] + (size_t)n * GNH;
        const unsigned short* ss = TSs[s] + (size_t)n * GNH;
#pragma unroll
        for (int i = 0; i < 2; ++i) {
            const int slab = wave * 2 + i;  // 8 slabs of 8 b-rows
            load_lds16(xs + (slab * 8 + lr) * 64 + lsw * 8, &XsX[slab * 512]);
            load_lds16(ss + (slab * 8 + lr) * 64 + lsw * 8, &XsS[slab * 512]);
        }
        __syncthreads();
#pragma unroll
        for (int ks = 0; ks < 4; ++ks) {
            const int kseg = ks * 4 + quad;  // 0..15
            half8_t b[2];
            b[0] = *(const half8_t*)&wbase[((s * 4 + ks) * 2 + 0) * 512];
            b[1] = *(const half8_t*)&wbase[((s * 4 + ks) * 2 + 1) * 512];
            const unsigned short* plane = (kseg < 8) ? XsX : XsS;
            const int aslot = ((kseg & 7) ^ (l15 & 7)) * 8;
#pragma unroll
            for (int mi = 0; mi < 4; ++mi) {
                const half8_t a =
                    *(const half8_t*)&plane[(mi * 16 + l15) * 64 + aslot];
#pragma unroll
                for (int ni = 0; ni < 2; ++ni)
                    acc[mi][ni] = __builtin_amdgcn_mfma_f32_16x16x32_f16(
                        a, b[ni], acc[mi][ni], 0, 0, 0);
            }
        }
        __syncthreads();
    }

#pragma unroll
    for (int mi = 0; mi < 4; ++mi) {
#pragma unroll
        for (int r = 0; r < 4; ++r) {
            const int b_g = mi * 16 + quad * 4 + r;
#pragma unroll
            for (int ni = 0; ni < 2; ++ni) {
                const int o_g = wn + ni * 16 + l15;
                const float v = sigmoidf_(acc[mi][ni][r] + bias[ni]);
                if (o_g < 64) {  // z -> candidate state slice
                    const float sv =
                        state[((size_t)b_g * N_NODES + n) * 64 + o_g];
                    cand[(size_t)n * GNH + b_g * 64 + o_g] = f2h(v * sv);
                } else {  // r
                    rbuf[((size_t)n * B_SZ + b_g) * 64 + (o_g - 64)] = f2h(v);
                }
            }
        }
    }
}

// ---------------------------------------------------------------------------
// Update per-node GEMM: out = r*state + (1-r)*tanh(acc+bias). N=64.
// Stream-ordered W layout (12KB contiguous per wave). S0 plane from CAND.
// ---------------------------------------------------------------------------
__global__ __launch_bounds__(256) void pernode_upd_kernel(
    const unsigned short* __restrict__ TX0,
    const unsigned short* __restrict__ CAND,
    const unsigned short* __restrict__ TX1,
    const unsigned short* __restrict__ TS1,
    const unsigned short* __restrict__ TX2,
    const unsigned short* __restrict__ TS2,
    const unsigned short* __restrict__ Wt, const float* __restrict__ E,
    const float* __restrict__ bp, const float* __restrict__ state,
    const unsigned short* __restrict__ rbuf, float* __restrict__ out) {
    __shared__ unsigned short XsX[64 * 64];
    __shared__ unsigned short XsS[64 * 64];
    const int n = blockIdx.x;
    const int tid = threadIdx.x;
    const int wave = tid >> 6;
    const int lane = tid & 63;
    const int l15 = lane & 15;
    const int quad = lane >> 4;
    const int wn = wave * 16;
    const int o_g = wn + l15;
    const int lr = lane >> 3;
    const int lsw = (lane & 7) ^ lr;

    float bias = 0.f;
#pragma unroll
    for (int e = 0; e < EDIM; ++e)
        bias += E[n * EDIM + e] * bp[e * 64 + o_g];

    f32x4 acc[4] = {};

    const unsigned short* TXs[3] = {TX0, TX1, TX2};
    const unsigned short* TSs[3] = {CAND, TS1, TS2};
    const unsigned short* wbase =
        Wt + ((size_t)n * 4 + wave) * WU_WAVE + lane * 8;

    for (int s = 0; s < 3; ++s) {
        const unsigned short* xs = TXs[s] + (size_t)n * GNH;
        const unsigned short* ss = TSs[s] + (size_t)n * GNH;
#pragma unroll
        for (int i = 0; i < 2; ++i) {
            const int slab = wave * 2 + i;
            load_lds16(xs + (slab * 8 + lr) * 64 + lsw * 8, &XsX[slab * 512]);
            load_lds16(ss + (slab * 8 + lr) * 64 + lsw * 8, &XsS[slab * 512]);
        }
        __syncthreads();
#pragma unroll
        for (int ks = 0; ks < 4; ++ks) {
            const int kseg = ks * 4 + quad;
            const half8_t b = *(const half8_t*)&wbase[(s * 4 + ks) * 512];
            const unsigned short* plane = (kseg < 8) ? XsX : XsS;
            const int aslot = ((kseg & 7) ^ (l15 & 7)) * 8;
#pragma unroll
            for (int mi = 0; mi < 4; ++mi) {
                const half8_t a =
                    *(const half8_t*)&plane[(mi * 16 + l15) * 64 + aslot];
                acc[mi] = __builtin_amdgcn_mfma_f32_16x16x32_f16(a, b, acc[mi],
                                                                 0, 0, 0);
            }
        }
        __syncthreads();
    }

#pragma unroll
    for (int mi = 0; mi < 4; ++mi) {
#pragma unroll
        for (int r = 0; r < 4; ++r) {
            const int b_g = mi * 16 + quad * 4 + r;
            const float hc = tanhf(acc[mi][r] + bias);
            const float rr = h2f(rbuf[((size_t)n * B_SZ + b_g) * 64 + o_g]);
            const float sv = state[((size_t)b_g * N_NODES + n) * 64 + o_g];
            out[((size_t)b_g * N_NODES + n) * 64 + o_g] =
                rr * sv + (1.f - rr) * hc;
        }
    }
}

// ---------------------------------------------------------------------------
extern "C" void kernel_launch(void* const* d_in, const int* in_sizes, int n_in,
                              void* d_out, int out_size, void* d_ws,
                              size_t ws_size, hipStream_t stream) {
    const float* x = (const float*)d_in[0];
    const float* state = (const float*)d_in[1];
    const float* E = (const float*)d_in[2];
    const float* gW = (const float*)d_in[3];  // (16,3,128,128)
    const float* gb = (const float*)d_in[4];  // (16,128)
    const float* uW = (const float*)d_in[5];  // (16,3,128,64)
    const float* ub = (const float*)d_in[6];  // (16,64)
    float* out = (float*)d_out;

    char* ws = (char*)d_ws;
    unsigned short* Ah = (unsigned short*)ws;                 //  2.10 MB
    unsigned short* AhT = (unsigned short*)(ws + 2097152);    //  2.10 MB
    unsigned short* S2h = (unsigned short*)(ws + 4194304);    //  2.10 MB
    unsigned short* TX0 = (unsigned short*)(ws + 6291456);    //  8.39 MB each
    unsigned short* TS0 = (unsigned short*)(ws + 14680064);
    unsigned short* TX0T = (unsigned short*)(ws + 23068672);
    unsigned short* TS0T = (unsigned short*)(ws + 31457280);
    unsigned short* TX1 = (unsigned short*)(ws + 39845888);
    unsigned short* TS1 = (unsigned short*)(ws + 48234496);
    unsigned short* TX2 = (unsigned short*)(ws + 56623104);
    unsigned short* TS2 = (unsigned short*)(ws + 65011712);
    unsigned short* WtG = (unsigned short*)(ws + 73400320);   // 100.66 MB
    unsigned short* rbuf = (unsigned short*)(ws + 174063616); //   8.39 MB
    unsigned short* CAND = (unsigned short*)(ws + 182452224); //   8.39 MB
    unsigned short* WtU = (unsigned short*)(ws + 190840832);  //  50.33 MB
    // total 241.2 MB (ws = 256 MB)

    // K1: all input-only work in ONE grid-partitioned launch (role-striped)
    fused_prep_kernel<<<4352, 256, 0, stream>>>(
        x, state, E, gW, uW, Ah, TX0, TS0, TX0T, TS0T, WtG, WtU);
    // K2: Ah -> AhT
    transpose16_kernel<<<dim3(16, 16), 256, 0, stream>>>(Ah, AhT, N_NODES);
    // K3: S2 = 2A^2 - I
    gemm_s2_kernel<<<dim3(16, 16), 256, 0, stream>>>(Ah, AhT, S2h);

    // --- avwgcn #1 (gate) ---
    gemm_graph8_kernel<256><<<256, 512, 0, stream>>>(
        Ah, S2h, TX0T, TS0T, TX1, TS1, TX2, TS2, 16, 4);
    pernode_gate_kernel<<<N_NODES, 256, 0, stream>>>(
        TX0, TS0, TX1, TS1, TX2, TS2, WtG, E, gb, state, rbuf, CAND);
    // regenerate TS0T (coalesced) from the candidate state slice
    transpose16_kernel<<<dim3(16, 64), 256, 0, stream>>>(CAND, TS0T, GNH);

    // --- avwgcn #2 (update): x-half of T1/T2 unchanged — S columns only ---
    gemm_graph8_kernel<128><<<256, 512, 0, stream>>>(
        Ah, S2h, TX0T, TS0T, TX1, TS1, TX2, TS2, 0, 2);
    pernode_upd_kernel<<<N_NODES, 256, 0, stream>>>(
        TX0, CAND, TX1, TS1, TX2, TS2, WtU, E, ub, state, rbuf, out);
}

// Round 16
// 263.471 us; speedup vs baseline: 1.0504x; 1.0504x over previous
//
#include <hip/hip_runtime.h>
#include <math.h>

#define N_NODES 1024
#define B_SZ 64
#define GNH 4096     // half-width: b*64+c layout for X or S plane
#define KI 384       // 3*128
#define EDIM 16
// stream-ordered Wt layouts (fp16 units per node)
#define WG_NODE 49152   // gate: 128 o x 384 k
#define WG_WAVE 12288   // per (n,wave)
#define WU_NODE 24576   // upd: 64 o x 384 k
#define WU_WAVE 6144

typedef _Float16 half8_t __attribute__((ext_vector_type(8)));
typedef float f32x4 __attribute__((ext_vector_type(4)));

__device__ __forceinline__ unsigned short f2h(float f) {
    _Float16 h = (_Float16)f;
    return *(unsigned short*)&h;
}
__device__ __forceinline__ float h2f(unsigned short u) {
    _Float16 h = *(_Float16*)&u;
    return (float)h;
}
__device__ __forceinline__ float sigmoidf_(float v) {
    return 1.f / (1.f + __expf(-v));
}
// async global->LDS, 16B per lane; lds base must be wave-uniform.
__device__ __forceinline__ void load_lds16(const void* g, void* l) {
    __builtin_amdgcn_global_load_lds(
        (const __attribute__((address_space(1))) void*)g,
        (__attribute__((address_space(3))) void*)l, 16, 0, 0);
}

// ---------------------------------------------------------------------------
// FUSED PREP (grid-partitioned, NO cross-role barriers -- each block runs
// exactly one role, chosen by blockIdx.x range):
//   [0,1024)     compute_A   : Ah = softmax(relu(E E^T)) rows
//   [1024,2048)  build_T0    : TX0/TS0 + TX0T/TS0T from x,state
//   [2048,3584)  dequant gate: WtG (stream-ordered)
//   [3584,4352)  dequant upd : WtU (stream-ordered)
// All four are mutually independent (inputs only); fusing overlaps their
// memory phases and removes 3 launch overheads. (R13-proven best config;
// striping (R15) and launch_bounds min-occupancy (R14) both regressed.)
// ---------------------------------------------------------------------------
__global__ __launch_bounds__(256) void fused_prep_kernel(
    const float* __restrict__ x, const float* __restrict__ state,
    const float* __restrict__ E, const float* __restrict__ gW,
    const float* __restrict__ uW, unsigned short* __restrict__ Ah,
    unsigned short* __restrict__ TX0, unsigned short* __restrict__ TS0,
    unsigned short* __restrict__ TX0T, unsigned short* __restrict__ TS0T,
    unsigned short* __restrict__ WtG, unsigned short* __restrict__ WtU) {
    __shared__ __align__(16) unsigned short sh[64 * 72 * 2];  // 18 KB scratch
    const int tid = threadIdx.x;
    const int blk = blockIdx.x;

    if (blk < 1024) {
        // ===================== compute_A =====================
        float* red = (float*)sh;
        const int n = blk;
        float en[EDIM];
#pragma unroll
        for (int e = 0; e < EDIM; ++e) en[e] = E[n * EDIM + e];
        float logit[4], lmax = -1e30f;
#pragma unroll
        for (int j = 0; j < 4; ++j) {
            const int m = tid + j * 256;
            float d = 0.f;
#pragma unroll
            for (int e = 0; e < EDIM; ++e) d += en[e] * E[m * EDIM + e];
            d = fmaxf(d, 0.f);
            logit[j] = d;
            lmax = fmaxf(lmax, d);
        }
        red[tid] = lmax;
        __syncthreads();
        for (int s = 128; s > 0; s >>= 1) {
            if (tid < s) red[tid] = fmaxf(red[tid], red[tid + s]);
            __syncthreads();
        }
        lmax = red[0];
        __syncthreads();
        float ex[4], lsum = 0.f;
#pragma unroll
        for (int j = 0; j < 4; ++j) {
            ex[j] = __expf(logit[j] - lmax);
            lsum += ex[j];
        }
        red[tid] = lsum;
        __syncthreads();
        for (int s = 128; s > 0; s >>= 1) {
            if (tid < s) red[tid] += red[tid + s];
            __syncthreads();
        }
        const float inv = 1.f / red[0];
#pragma unroll
        for (int j = 0; j < 4; ++j)
            Ah[n * N_NODES + tid + j * 256] = f2h(ex[j] * inv);
    } else if (blk < 2048) {
        // ===================== build_T0 =====================
        unsigned short* Lx = sh;             // [c][nl] pad 72
        unsigned short* Lss = sh + 64 * 72;
        const int idx = blk - 1024;
        const int n0 = (idx & 15) * 64;
        const int b = idx >> 4;
#pragma unroll
        for (int t = 0; t < 16; ++t) {
            const int id = t * 256 + tid;
            const int nl = id >> 6;
            const int c = id & 63;
            const float xv = x[((size_t)b * N_NODES + n0 + nl) * 64 + c];
            const float sv = state[((size_t)b * N_NODES + n0 + nl) * 64 + c];
            const unsigned short xh = f2h(xv), shv = f2h(sv);
            TX0[(size_t)(n0 + nl) * GNH + b * 64 + c] = xh;
            TS0[(size_t)(n0 + nl) * GNH + b * 64 + c] = shv;
            Lx[c * 72 + nl] = xh;
            Lss[c * 72 + nl] = shv;
        }
        __syncthreads();
#pragma unroll
        for (int t = 0; t < 2; ++t) {
            const int id = t * 256 + tid;
            const int c = id >> 3;
            const int n8 = id & 7;
            uint4 xv = *(const uint4*)&Lx[c * 72 + n8 * 8];
            uint4 sv = *(const uint4*)&Lss[c * 72 + n8 * 8];
            *(uint4*)&TX0T[(size_t)(b * 64 + c) * N_NODES + n0 + n8 * 8] = xv;
            *(uint4*)&TS0T[(size_t)(b * 64 + c) * N_NODES + n0 + n8 * 8] = sv;
        }
    } else if (blk < 3584) {
        // ===================== dequant gate =====================
        float* En = (float*)sh;
        const int idx = blk - 2048;
        const int c8 = (idx % 48) * 256 + tid;  // 0..12287
        const int n0 = (idx / 48) * 32;
        const int sub = c8 & 1;
        const int c = c8 >> 1;
        const int l15 = c & 15;
        const int quad = (c >> 4) & 3;
        const int half = (c >> 6) & 1;
        const int ks = (c >> 7) & 3;
        const int sq = c >> 9;
        const int s = sq % 3;
        const int w = sq / 3;
        const int k0 = s * 128 + (ks * 4 + quad) * 8 + sub * 4;
        const int o = w * 32 + half * 16 + l15;
#pragma unroll
        for (int t = 0; t < 2; ++t) {
            const int id = t * 256 + tid;
            En[id] = E[(n0 + (id >> 4)) * EDIM + (id & 15)];
        }
        __syncthreads();
        f32x4 wv[EDIM];
#pragma unroll
        for (int e = 0; e < EDIM; ++e) {
            f32x4 v;
#pragma unroll
            for (int j = 0; j < 4; ++j)
                v[j] = gW[(size_t)(e * KI + k0 + j) * 128 + o];
            wv[e] = v;
        }
#pragma unroll 4
        for (int nl = 0; nl < 32; ++nl) {
            f32x4 a = {0.f, 0.f, 0.f, 0.f};
#pragma unroll
            for (int e = 0; e < EDIM; ++e) a += wv[e] * En[nl * EDIM + e];
            union { unsigned short u[4]; uint2 v; } pk;
#pragma unroll
            for (int j = 0; j < 4; ++j) pk.u[j] = f2h(a[j]);
            *(uint2*)&WtG[(size_t)(n0 + nl) * WG_NODE + (size_t)c8 * 4] = pk.v;
        }
    } else {
        // ===================== dequant upd =====================
        float* En = (float*)sh;
        const int idx = blk - 3584;
        const int c8 = (idx % 24) * 256 + tid;  // 0..6143
        const int n0 = (idx / 24) * 32;
        const int sub = c8 & 1;
        const int c = c8 >> 1;
        const int l15 = c & 15;
        const int quad = (c >> 4) & 3;
        const int ks = (c >> 6) & 3;
        const int sq = c >> 8;
        const int s = sq % 3;
        const int w = sq / 3;
        const int k0 = s * 128 + (ks * 4 + quad) * 8 + sub * 4;
        const int o = w * 16 + l15;
#pragma unroll
        for (int t = 0; t < 2; ++t) {
            const int id = t * 256 + tid;
            En[id] = E[(n0 + (id >> 4)) * EDIM + (id & 15)];
        }
        __syncthreads();
        f32x4 wv[EDIM];
#pragma unroll
        for (int e = 0; e < EDIM; ++e) {
            f32x4 v;
#pragma unroll
            for (int j = 0; j < 4; ++j)
                v[j] = uW[(size_t)(e * KI + k0 + j) * 64 + o];
            wv[e] = v;
        }
#pragma unroll 4
        for (int nl = 0; nl < 32; ++nl) {
            f32x4 a = {0.f, 0.f, 0.f, 0.f};
#pragma unroll
            for (int e = 0; e < EDIM; ++e) a += wv[e] * En[nl * EDIM + e];
            union { unsigned short u[4]; uint2 v; } pk;
#pragma unroll
            for (int j = 0; j < 4; ++j) pk.u[j] = f2h(a[j]);
            *(uint2*)&WtU[(size_t)(n0 + nl) * WU_NODE + (size_t)c8 * 4] = pk.v;
        }
    }
}

// ---------------------------------------------------------------------------
// Generic fp16 transpose: dst[c][1024] = src[r][W], 64x64 tiles.
// ---------------------------------------------------------------------------
__global__ __launch_bounds__(256) void transpose16_kernel(
    const unsigned short* __restrict__ src, unsigned short* __restrict__ dst,
    int W) {
    __shared__ unsigned short Ls[64 * 72];
    const int tid = threadIdx.x;
    const int r0 = blockIdx.x * 64;
    const int c0 = blockIdx.y * 64;
#pragma unroll
    for (int t = 0; t < 2; ++t) {
        const int id = t * 256 + tid;
        const int row = id >> 3;
        const int c8 = id & 7;
        uint4 v = *(const uint4*)&src[(size_t)(r0 + row) * W + c0 + c8 * 8];
        const unsigned short* vp = (const unsigned short*)&v;
#pragma unroll
        for (int j = 0; j < 8; ++j) Ls[(c8 * 8 + j) * 72 + row] = vp[j];
    }
    __syncthreads();
#pragma unroll
    for (int t = 0; t < 2; ++t) {
        const int id = t * 256 + tid;
        const int c = id >> 3;
        const int r8 = id & 7;
        uint4 v = *(const uint4*)&Ls[c * 72 + r8 * 8];
        *(uint4*)&dst[(size_t)(c0 + c) * N_NODES + r0 + r8 * 8] = v;
    }
}

// ---------------------------------------------------------------------------
// S2h[n][m] = 2 * sum_k Ah[n][k]*AhT[m][k] - (n==m)   (S2 = 2A^2 - I)
// ---------------------------------------------------------------------------
__global__ __launch_bounds__(256) void gemm_s2_kernel(
    const unsigned short* __restrict__ Ah,
    const unsigned short* __restrict__ AhT, unsigned short* __restrict__ S2h) {
    __shared__ unsigned short As[64 * 64];
    __shared__ unsigned short Bs[64 * 64];
    const int tid = threadIdx.x;
    const int wave = tid >> 6;
    const int lane = tid & 63;
    const int l15 = lane & 15;
    const int quad = lane >> 4;
    const int n0 = blockIdx.x * 64;
    const int m0 = blockIdx.y * 64;
    const int wn = wave * 16;
    const int lr = lane >> 3;
    const int lsw = (lane & 7) ^ lr;

    f32x4 acc[4] = {};
    for (int k0 = 0; k0 < N_NODES; k0 += 64) {
#pragma unroll
        for (int i = 0; i < 2; ++i) {
            const int rbase = (wave * 2 + i) * 8;
            load_lds16(&Ah[(size_t)(n0 + rbase + lr) * N_NODES + k0 + lsw * 8],
                       &As[rbase * 64]);
            load_lds16(&AhT[(size_t)(m0 + rbase + lr) * N_NODES + k0 + lsw * 8],
                       &Bs[rbase * 64]);
        }
        __syncthreads();
#pragma unroll
        for (int ks = 0; ks < 2; ++ks) {
            const int slot = ((ks * 4 + quad) ^ (l15 & 7)) * 8;
            const half8_t b = *(const half8_t*)&Bs[(wn + l15) * 64 + slot];
#pragma unroll
            for (int mi = 0; mi < 4; ++mi) {
                const half8_t a = *(const half8_t*)&As[(mi * 16 + l15) * 64 + slot];
                acc[mi] =
                    __builtin_amdgcn_mfma_f32_16x16x32_f16(a, b, acc[mi], 0, 0, 0);
            }
        }
        __syncthreads();
    }
#pragma unroll
    for (int mi = 0; mi < 4; ++mi) {
#pragma unroll
        for (int r = 0; r < 4; ++r) {
            const int n_g = n0 + mi * 16 + quad * 4 + r;
            const int m_g = m0 + wn + l15;
            const float v = 2.f * acc[mi][r] - (n_g == m_g ? 1.f : 0.f);
            S2h[(size_t)n_g * N_NODES + m_g] = f2h(v);
        }
    }
}

// ---------------------------------------------------------------------------
// Graph GEMM, pipelined ring-4 with SINGLE phase per K-tile (R8-proven):
//   {ds_read all 8A+4B frags || stage A+B(t+3) -> lgkm0 -> setprio(1)
//    32 MFMA setprio(0) -> counted vmcnt -> ONE barrier}.
// ---------------------------------------------------------------------------
template <int BM>
__global__ __launch_bounds__(512, 2) void gemm_graph8_kernel(
    const unsigned short* __restrict__ Ah,
    const unsigned short* __restrict__ S2h,
    const unsigned short* __restrict__ BTX,
    const unsigned short* __restrict__ BTS,
    unsigned short* __restrict__ T1X, unsigned short* __restrict__ T1S,
    unsigned short* __restrict__ T2X, unsigned short* __restrict__ T2S,
    int ysplit, int colsPerXcd) {
    constexpr int MFR = BM / 32;        // A frags per wave (8 or 4)
    constexpr int ASLOT_H = BM * 32;    // f16 per A slot (BM/2 prows x 64)
    constexpr int SLOT_H = ASLOT_H + 8192;  // + B slot (128 prows x 64)
    constexpr int APASS = BM / 128;     // stage passes for A (2 or 1)
    constexpr int MT = 2048 / BM;       // row tiles
    __shared__ unsigned short lds[4 * SLOT_H];  // 128 KB (BM=256) / 96 KB

    const int tid = threadIdx.x;
    const int wave = tid >> 6;
    const int lane = tid & 63;
    const int l15 = lane & 15;
    const int quad = lane >> 4;
    const int wm = (wave >> 2) * (BM / 2);
    const int wn = (wave & 3) * 64;

    // XCD-locality swizzle: xcd owns colsPerXcd 256-col tiles x all row tiles
    const int id = blockIdx.x;
    const int xcd = id & 7;
    const int j = id >> 3;
    const int mtile = j & (MT - 1);
    const int ytile = xcd * colsPerXcd + j / MT;
    const int mrow0 = mtile * BM;
    const bool isA = mrow0 < N_NODES;
    const unsigned short* Asrc =
        (isA ? Ah : S2h) + (size_t)(mrow0 & 1023) * N_NODES;
    const bool isX = ytile < ysplit;
    const int col0 = (isX ? ytile : ytile - ysplit) * 256;
    const unsigned short* Bsrc = (isX ? BTX : BTS) + (size_t)col0 * N_NODES;
    unsigned short* OUT = (isA ? (isX ? T1X : T1S) : (isX ? T2X : T2S)) +
                          (size_t)(mrow0 & 1023) * GNH + col0;

    // stage source offsets: physical cell (prow, s) <- logical
    // (row = 2*prow + half, kslot) with half*4+kslot = s ^ (prow&7)
    int goff[2];
#pragma unroll
    for (int jp = 0; jp < 2; ++jp) {
        const int cell = jp * 512 + tid;
        const int prow = cell >> 3;
        const int q = (cell & 7) ^ (prow & 7);
        goff[jp] = (2 * prow + (q >> 2)) * N_NODES + (q & 3) * 8;
    }

    // ds_read fragment offsets (f16 units): row R -> prow=R>>1, half=R&1,
    // s8 = (half*4 + quad) ^ (prow&7)
    int offA[MFR], offB[4];
#pragma unroll
    for (int mi = 0; mi < MFR; ++mi) {
        const int prow = (wm >> 1) + mi * 8 + (l15 >> 1);
        const int s8 = ((l15 & 1) * 4 + quad) ^ (prow & 7);
        offA[mi] = prow * 64 + s8 * 8;
    }
#pragma unroll
    for (int ni = 0; ni < 4; ++ni) {
        const int pcol = (wn >> 1) + ni * 8 + (l15 >> 1);
        const int s8 = ((l15 & 1) * 4 + quad) ^ (pcol & 7);
        offB[ni] = ASLOT_H + pcol * 64 + s8 * 8;
    }

    f32x4 acc[MFR][4] = {};

    auto stageA = [&](int t) {
        const int sl = t & 3;
#pragma unroll
        for (int jp = 0; jp < APASS; ++jp)
            load_lds16(Asrc + (size_t)t * 32 + goff[jp],
                       &lds[sl * SLOT_H + jp * 4096 + wave * 512]);
    };
    auto stageB = [&](int t) {
        const int sl = t & 3;
#pragma unroll
        for (int jp = 0; jp < 2; ++jp)
            load_lds16(Bsrc + (size_t)t * 32 + goff[jp],
                       &lds[sl * SLOT_H + ASLOT_H + jp * 4096 + wave * 512]);
    };
    // counted vmcnt: allow the newest 2 tiles' stages (2*LPT instrs) in flight
    auto waitPipe = [&] {
        if constexpr (BM == 256)
            asm volatile("s_waitcnt vmcnt(8)" ::: "memory");
        else
            asm volatile("s_waitcnt vmcnt(6)" ::: "memory");
    };

    auto tileBody = [&](int t, bool tail) {
        const unsigned short* base = &lds[(t & 3) * SLOT_H];
        half8_t a[MFR], b[4];
        // read ALL fragments for this tile (slot certified by prev barrier)
#pragma unroll
        for (int mi = 0; mi < MFR; ++mi)
            a[mi] = *(const half8_t*)&base[offA[mi]];
#pragma unroll
        for (int ni = 0; ni < 4; ++ni)
            b[ni] = *(const half8_t*)&base[offB[ni]];
        // issue next-tile stages (write slot (t-1)&3: safe -- all waves
        // passed lgkm0 for tile t-1 before the trailing barrier of t-1)
        if (!tail) {
            stageA(t + 3);
            stageB(t + 3);
        }
        __builtin_amdgcn_sched_barrier(0);
        asm volatile("s_waitcnt lgkmcnt(0)" ::: "memory");
        __builtin_amdgcn_sched_barrier(0);
        __builtin_amdgcn_s_setprio(1);
#pragma unroll
        for (int mi = 0; mi < MFR; ++mi)
#pragma unroll
            for (int ni = 0; ni < 4; ++ni)
                acc[mi][ni] = __builtin_amdgcn_mfma_f32_16x16x32_f16(
                    a[mi], b[ni], acc[mi][ni], 0, 0, 0);
        __builtin_amdgcn_s_setprio(0);
        __builtin_amdgcn_sched_barrier(0);
        if (!tail) {
            waitPipe();  // tile t+1 landed; t+2,t+3 stay in flight
        } else {
            asm volatile("s_waitcnt vmcnt(0)" ::: "memory");
        }
        __builtin_amdgcn_sched_barrier(0);
        __builtin_amdgcn_s_barrier();  // ONE barrier per K-tile
    };

    // prologue: stage tiles 0..2, wait for tile 0 (tiles 1,2 stay in flight)
    stageA(0); stageB(0);
    stageA(1); stageB(1);
    stageA(2); stageB(2);
    waitPipe();
    __builtin_amdgcn_s_barrier();
    __builtin_amdgcn_sched_barrier(0);

    // K = 1024 -> 32 tiles of BK=32
#pragma unroll 4
    for (int t = 0; t < 28; ++t) tileBody(t, false);
    tileBody(28, false);
    tileBody(29, true);
    tileBody(30, true);
    tileBody(31, true);

    // epilogue: 64-row passes through LDS repack -> coalesced uint4 stores
    constexpr int NPASS = BM / 64;
#pragma unroll
    for (int p = 0; p < NPASS; ++p) {
        __syncthreads();
        const int whalf = (BM == 256) ? (p >> 1) : p;
        const int mi0 = (BM == 256) ? (p & 1) * 4 : 0;
        if ((wave >> 2) == whalf) {
#pragma unroll
            for (int mi = 0; mi < 4; ++mi)
#pragma unroll
                for (int ni = 0; ni < 4; ++ni)
#pragma unroll
                    for (int r = 0; r < 4; ++r) {
                        const int row = mi * 16 + quad * 4 + r;
                        const int col = wn + ni * 16 + l15;
                        lds[row * 264 + col] = f2h(acc[mi0 + mi][ni][r]);
                    }
        }
        __syncthreads();
#pragma unroll
        for (int i = 0; i < 4; ++i) {
            const int id2 = i * 512 + tid;
            const int row = id2 >> 5;
            const int c8 = id2 & 31;
            uint4 v = *(const uint4*)&lds[row * 264 + c8 * 8];
            *(uint4*)&OUT[(size_t)(p * 64 + row) * GNH + c8 * 8] = v;
        }
    }
}

// ---------------------------------------------------------------------------
// Gate per-node GEMM (merged z+r): M=64(b), N=128(o), K=384. R2 schedule,
// W reads from the stream-ordered layout: contiguous 1KB per instruction,
// contiguous 24KB per wave. z -> CAND (z*state), r -> rbuf.
// ---------------------------------------------------------------------------
__global__ __launch_bounds__(256) void pernode_gate_kernel(
    const unsigned short* __restrict__ TX0,
    const unsigned short* __restrict__ TS0,
    const unsigned short* __restrict__ TX1,
    const unsigned short* __restrict__ TS1,
    const unsigned short* __restrict__ TX2,
    const unsigned short* __restrict__ TS2,
    const unsigned short* __restrict__ Wt, const float* __restrict__ E,
    const float* __restrict__ bp, const float* __restrict__ state,
    unsigned short* __restrict__ rbuf, unsigned short* __restrict__ cand) {
    __shared__ unsigned short XsX[64 * 64];  // [b][kseg 0..7] swizzled
    __shared__ unsigned short XsS[64 * 64];  // [b][kseg 8..15] swizzled
    const int n = blockIdx.x;
    const int tid = threadIdx.x;
    const int wave = tid >> 6;
    const int lane = tid & 63;
    const int l15 = lane & 15;
    const int quad = lane >> 4;
    const int wn = wave * 32;
    const int lr = lane >> 3;
    const int lsw = (lane & 7) ^ lr;

    float bias[2];
#pragma unroll
    for (int ni = 0; ni < 2; ++ni) {
        float bv = 0.f;
#pragma unroll
        for (int e = 0; e < EDIM; ++e)
            bv += E[n * EDIM + e] * bp[e * 128 + wn + ni * 16 + l15];
        bias[ni] = bv;
    }

    f32x4 acc[4][2] = {};

    const unsigned short* TXs[3] = {TX0, TX1, TX2};
    const unsigned short* TSs[3] = {TS0, TS1, TS2};
    const unsigned short* wbase =
        Wt + ((size_t)n * 4 + wave) * WG_WAVE + lane * 8;

    for (int s = 0; s < 3; ++s) {
        const unsigned short* xs = TXs[s] + (size_t)n * GNH;
        const unsigned short* ss = TSs[s] + (size_t)n * GNH;
#pragma unroll
        for (int i = 0; i < 2; ++i) {
            const int slab = wave * 2 + i;  // 8 slabs of 8 b-rows
            load_lds16(xs + (slab * 8 + lr) * 64 + lsw * 8, &XsX[slab * 512]);
            load_lds16(ss + (slab * 8 + lr) * 64 + lsw * 8, &XsS[slab * 512]);
        }
        __syncthreads();
#pragma unroll
        for (int ks = 0; ks < 4; ++ks) {
            const int kseg = ks * 4 + quad;  // 0..15
            half8_t b[2];
            b[0] = *(const half8_t*)&wbase[((s * 4 + ks) * 2 + 0) * 512];
            b[1] = *(const half8_t*)&wbase[((s * 4 + ks) * 2 + 1) * 512];
            const unsigned short* plane = (kseg < 8) ? XsX : XsS;
            const int aslot = ((kseg & 7) ^ (l15 & 7)) * 8;
#pragma unroll
            for (int mi = 0; mi < 4; ++mi) {
                const half8_t a =
                    *(const half8_t*)&plane[(mi * 16 + l15) * 64 + aslot];
#pragma unroll
                for (int ni = 0; ni < 2; ++ni)
                    acc[mi][ni] = __builtin_amdgcn_mfma_f32_16x16x32_f16(
                        a, b[ni], acc[mi][ni], 0, 0, 0);
            }
        }
        __syncthreads();
    }

#pragma unroll
    for (int mi = 0; mi < 4; ++mi) {
#pragma unroll
        for (int r = 0; r < 4; ++r) {
            const int b_g = mi * 16 + quad * 4 + r;
#pragma unroll
            for (int ni = 0; ni < 2; ++ni) {
                const int o_g = wn + ni * 16 + l15;
                const float v = sigmoidf_(acc[mi][ni][r] + bias[ni]);
                if (o_g < 64) {  // z -> candidate state slice
                    const float sv =
                        state[((size_t)b_g * N_NODES + n) * 64 + o_g];
                    cand[(size_t)n * GNH + b_g * 64 + o_g] = f2h(v * sv);
                } else {  // r
                    rbuf[((size_t)n * B_SZ + b_g) * 64 + (o_g - 64)] = f2h(v);
                }
            }
        }
    }
}

// ---------------------------------------------------------------------------
// Update per-node GEMM: out = r*state + (1-r)*tanh(acc+bias). N=64.
// Stream-ordered W layout (12KB contiguous per wave). S0 plane from CAND.
// ---------------------------------------------------------------------------
__global__ __launch_bounds__(256) void pernode_upd_kernel(
    const unsigned short* __restrict__ TX0,
    const unsigned short* __restrict__ CAND,
    const unsigned short* __restrict__ TX1,
    const unsigned short* __restrict__ TS1,
    const unsigned short* __restrict__ TX2,
    const unsigned short* __restrict__ TS2,
    const unsigned short* __restrict__ Wt, const float* __restrict__ E,
    const float* __restrict__ bp, const float* __restrict__ state,
    const unsigned short* __restrict__ rbuf, float* __restrict__ out) {
    __shared__ unsigned short XsX[64 * 64];
    __shared__ unsigned short XsS[64 * 64];
    const int n = blockIdx.x;
    const int tid = threadIdx.x;
    const int wave = tid >> 6;
    const int lane = tid & 63;
    const int l15 = lane & 15;
    const int quad = lane >> 4;
    const int wn = wave * 16;
    const int o_g = wn + l15;
    const int lr = lane >> 3;
    const int lsw = (lane & 7) ^ lr;

    float bias = 0.f;
#pragma unroll
    for (int e = 0; e < EDIM; ++e)
        bias += E[n * EDIM + e] * bp[e * 64 + o_g];

    f32x4 acc[4] = {};

    const unsigned short* TXs[3] = {TX0, TX1, TX2};
    const unsigned short* TSs[3] = {CAND, TS1, TS2};
    const unsigned short* wbase =
        Wt + ((size_t)n * 4 + wave) * WU_WAVE + lane * 8;

    for (int s = 0; s < 3; ++s) {
        const unsigned short* xs = TXs[s] + (size_t)n * GNH;
        const unsigned short* ss = TSs[s] + (size_t)n * GNH;
#pragma unroll
        for (int i = 0; i < 2; ++i) {
            const int slab = wave * 2 + i;
            load_lds16(xs + (slab * 8 + lr) * 64 + lsw * 8, &XsX[slab * 512]);
            load_lds16(ss + (slab * 8 + lr) * 64 + lsw * 8, &XsS[slab * 512]);
        }
        __syncthreads();
#pragma unroll
        for (int ks = 0; ks < 4; ++ks) {
            const int kseg = ks * 4 + quad;
            const half8_t b = *(const half8_t*)&wbase[(s * 4 + ks) * 512];
            const unsigned short* plane = (kseg < 8) ? XsX : XsS;
            const int aslot = ((kseg & 7) ^ (l15 & 7)) * 8;
#pragma unroll
            for (int mi = 0; mi < 4; ++mi) {
                const half8_t a =
                    *(const half8_t*)&plane[(mi * 16 + l15) * 64 + aslot];
                acc[mi] = __builtin_amdgcn_mfma_f32_16x16x32_f16(a, b, acc[mi],
                                                                 0, 0, 0);
            }
        }
        __syncthreads();
    }

#pragma unroll
    for (int mi = 0; mi < 4; ++mi) {
#pragma unroll
        for (int r = 0; r < 4; ++r) {
            const int b_g = mi * 16 + quad * 4 + r;
            const float hc = tanhf(acc[mi][r] + bias);
            const float rr = h2f(rbuf[((size_t)n * B_SZ + b_g) * 64 + o_g]);
            const float sv = state[((size_t)b_g * N_NODES + n) * 64 + o_g];
            out[((size_t)b_g * N_NODES + n) * 64 + o_g] =
                rr * sv + (1.f - rr) * hc;
        }
    }
}

// ---------------------------------------------------------------------------
extern "C" void kernel_launch(void* const* d_in, const int* in_sizes, int n_in,
                              void* d_out, int out_size, void* d_ws,
                              size_t ws_size, hipStream_t stream) {
    const float* x = (const float*)d_in[0];
    const float* state = (const float*)d_in[1];
    const float* E = (const float*)d_in[2];
    const float* gW = (const float*)d_in[3];  // (16,3,128,128)
    const float* gb = (const float*)d_in[4];  // (16,128)
    const float* uW = (const float*)d_in[5];  // (16,3,128,64)
    const float* ub = (const float*)d_in[6];  // (16,64)
    float* out = (float*)d_out;

    char* ws = (char*)d_ws;
    unsigned short* Ah = (unsigned short*)ws;                 //  2.10 MB
    unsigned short* AhT = (unsigned short*)(ws + 2097152);    //  2.10 MB
    unsigned short* S2h = (unsigned short*)(ws + 4194304);    //  2.10 MB
    unsigned short* TX0 = (unsigned short*)(ws + 6291456);    //  8.39 MB each
    unsigned short* TS0 = (unsigned short*)(ws + 14680064);
    unsigned short* TX0T = (unsigned short*)(ws + 23068672);
    unsigned short* TS0T = (unsigned short*)(ws + 31457280);
    unsigned short* TX1 = (unsigned short*)(ws + 39845888);
    unsigned short* TS1 = (unsigned short*)(ws + 48234496);
    unsigned short* TX2 = (unsigned short*)(ws + 56623104);
    unsigned short* TS2 = (unsigned short*)(ws + 65011712);
    unsigned short* WtG = (unsigned short*)(ws + 73400320);   // 100.66 MB
    unsigned short* rbuf = (unsigned short*)(ws + 174063616); //   8.39 MB
    unsigned short* CAND = (unsigned short*)(ws + 182452224); //   8.39 MB
    unsigned short* WtU = (unsigned short*)(ws + 190840832);  //  50.33 MB
    // total 241.2 MB (ws = 256 MB)

    // K1: all input-only work in ONE grid-partitioned launch
    fused_prep_kernel<<<4352, 256, 0, stream>>>(
        x, state, E, gW, uW, Ah, TX0, TS0, TX0T, TS0T, WtG, WtU);
    // K2: Ah -> AhT
    transpose16_kernel<<<dim3(16, 16), 256, 0, stream>>>(Ah, AhT, N_NODES);
    // K3: S2 = 2A^2 - I
    gemm_s2_kernel<<<dim3(16, 16), 256, 0, stream>>>(Ah, AhT, S2h);

    // --- avwgcn #1 (gate) ---
    gemm_graph8_kernel<256><<<256, 512, 0, stream>>>(
        Ah, S2h, TX0T, TS0T, TX1, TS1, TX2, TS2, 16, 4);
    pernode_gate_kernel<<<N_NODES, 256, 0, stream>>>(
        TX0, TS0, TX1, TS1, TX2, TS2, WtG, E, gb, state, rbuf, CAND);
    // regenerate TS0T (coalesced) from the candidate state slice
    transpose16_kernel<<<dim3(16, 64), 256, 0, stream>>>(CAND, TS0T, GNH);

    // --- avwgcn #2 (update): x-half of T1/T2 unchanged — S columns only ---
    gemm_graph8_kernel<128><<<256, 512, 0, stream>>>(
        Ah, S2h, TX0T, TS0T, TX1, TS1, TX2, TS2, 0, 2);
    pernode_upd_kernel<<<N_NODES, 256, 0, stream>>>(
        TX0, CAND, TX1, TS1, TX2, TS2, WtU, E, ub, state, rbuf, out);
}